// Round 5
// baseline (317.993 us; speedup 1.0000x reference)
//
#include <hip/hip_runtime.h>
#include <hip/hip_bf16.h>

typedef __bf16 bf16x8 __attribute__((ext_vector_type(8)));
typedef float  f32x4  __attribute__((ext_vector_type(4)));

// 512 threads = 8 waves per block; one output column-block c, 512 M-rows
// (64 per wave). B (4 nonzero 64x64 blocks of column c) staged ONCE to LDS
// (bf16, [s][n][k] transposed, XOR-swizzled) by all 8 waves; A fragments
// loaded directly from global (fp32), converted in-register. Main loop:
// 16 steps (mt x s), depth-2 prefetch. One barrier total; waves slip freely.
// __launch_bounds__(512,8): VGPR cap 64 -> 8 waves/SIMD -> 32 waves/CU with
// 4 resident blocks (4 x 32KB = 128KB LDS).
__global__ __launch_bounds__(512, 8) void sparse_linear_kernel(
    const float* __restrict__ A, const float* __restrict__ Bd,
    const int* __restrict__ rowi, const int* __restrict__ di,
    float* __restrict__ C)
{
    __shared__ __align__(16) unsigned short Bt[4 * 64 * 64];   // 32 KB
    char* BtB = (char*)Bt;

    const int bid = blockIdx.x;
    const int c   = bid & 63;          // m-chunk-major: A-panel sharers concurrent -> L3 reuse
    const int mch = bid >> 6;          // 0..15
    const int t    = threadIdx.x;
    const int lane = t & 63;
    const int w    = t >> 6;           // 0..7

    int rs[4], ds[4];
    #pragma unroll
    for (int s = 0; s < 4; ++s) {
        rs[s] = rowi[s * 64 + c];
        ds[s] = di[s * 64 + c];
    }
    int koff[4];
    #pragma unroll
    for (int s = 0; s < 4; ++s) koff[s] = rs[s] * 64;

    const long mbase = (long)mch * 512 + w * 64;
    const float* Abase = A + (mbase + (lane & 15)) * 4096 + (lane >> 4) * 8;

    // ---- prologue: prefetch steps 0 and 1 (mt=0; s=0,1) ----
    float4 pf[2][4];
    #pragma unroll
    for (int st = 0; st < 2; ++st) {
        const float* p = Abase + koff[st];
        pf[st][0] = *(const float4*)(p);
        pf[st][1] = *(const float4*)(p + 4);
        pf[st][2] = *(const float4*)(p + 32);
        pf[st][3] = *(const float4*)(p + 36);
    }

    // ---- stage B once: 8 waves, 2 per s-block; thread owns (col n, k-half) ----
    {
        const int n  = t & 63;
        const int kh = (t >> 6) & 1;       // k rows [kh*32, kh*32+32)
        const int sb = t >> 7;             // 0..3
        const float* Bg = Bd + (long)ds[sb] * 64 + (long)kh * 32 * 16384 + n;
        char* dst = BtB + sb * 8192 + n * 128;
        const int sw = (n & 7) << 4;
        #pragma unroll
        for (int k4 = 0; k4 < 8; ++k4) {
            union { ushort4 u; __bf16 e[4]; } pk;
            pk.e[0] = (__bf16)Bg[(long)(4 * k4 + 0) * 16384];
            pk.e[1] = (__bf16)Bg[(long)(4 * k4 + 1) * 16384];
            pk.e[2] = (__bf16)Bg[(long)(4 * k4 + 2) * 16384];
            pk.e[3] = (__bf16)Bg[(long)(4 * k4 + 3) * 16384];
            *(ushort4*)(dst + ((kh * 64 + 8 * k4) ^ sw)) = pk.u;
        }
    }
    __syncthreads();   // the only barrier

    f32x4 acc[4];
    #pragma unroll
    for (int n2 = 0; n2 < 4; ++n2) acc[n2] = f32x4{0.f, 0.f, 0.f, 0.f};

    #pragma unroll
    for (int step = 0; step < 16; ++step) {
        const int mt = step >> 2, s = step & 3, slot = step & 1;

        // convert this step's A fragments (consumes pf[slot])
        union { bf16x8 v; __bf16 e[8]; } af0, af1;
        {
            const float4 a0 = pf[slot][0], a1 = pf[slot][1];
            const float4 a2 = pf[slot][2], a3 = pf[slot][3];
            af0.e[0] = (__bf16)a0.x; af0.e[1] = (__bf16)a0.y;
            af0.e[2] = (__bf16)a0.z; af0.e[3] = (__bf16)a0.w;
            af0.e[4] = (__bf16)a1.x; af0.e[5] = (__bf16)a1.y;
            af0.e[6] = (__bf16)a1.z; af0.e[7] = (__bf16)a1.w;
            af1.e[0] = (__bf16)a2.x; af1.e[1] = (__bf16)a2.y;
            af1.e[2] = (__bf16)a2.z; af1.e[3] = (__bf16)a2.w;
            af1.e[4] = (__bf16)a3.x; af1.e[5] = (__bf16)a3.y;
            af1.e[6] = (__bf16)a3.z; af1.e[7] = (__bf16)a3.w;
        }

        // re-issue freed slot for step+2 (WAR orders this after the converts)
        if (step + 2 < 16) {
            const int mt2 = (step + 2) >> 2, s2 = (step + 2) & 3;
            const float* p = Abase + (long)mt2 * (16 * 4096) + koff[s2];
            pf[slot][0] = *(const float4*)(p);
            pf[slot][1] = *(const float4*)(p + 4);
            pf[slot][2] = *(const float4*)(p + 32);
            pf[slot][3] = *(const float4*)(p + 36);
        }

        // 8 MFMAs for this (mt, s)
        const char* bbase = BtB + s * 8192;
        __builtin_amdgcn_s_setprio(1);
        #pragma unroll
        for (int kh = 0; kh < 2; ++kh) {
            const bf16x8 afv = kh ? af1.v : af0.v;
            const int kb = kh * 64 + (lane >> 4) * 16;
            #pragma unroll
            for (int n2 = 0; n2 < 4; ++n2) {
                const int nr = n2 * 16 + (lane & 15);
                bf16x8 bf = *(const bf16x8*)(bbase + nr * 128 + (kb ^ ((nr & 7) << 4)));
                acc[n2] = __builtin_amdgcn_mfma_f32_16x16x32_bf16(afv, bf, acc[n2], 0, 0, 0);
            }
        }
        __builtin_amdgcn_s_setprio(0);

        // C write at end of each m-tile (NT: keep A/B resident in caches)
        if (s == 3) {
            const long crow0 = mbase + mt * 16 + (lane >> 4) * 4;
            const long col0  = (long)c * 64 + (lane & 15);
            #pragma unroll
            for (int n2 = 0; n2 < 4; ++n2) {
                #pragma unroll
                for (int v = 0; v < 4; ++v)
                    __builtin_nontemporal_store(acc[n2][v],
                        &C[(crow0 + v) * 4096 + col0 + n2 * 16]);
                acc[n2] = f32x4{0.f, 0.f, 0.f, 0.f};
            }
        }
    }
}

extern "C" void kernel_launch(void* const* d_in, const int* in_sizes, int n_in,
                              void* d_out, int out_size, void* d_ws, size_t ws_size,
                              hipStream_t stream) {
    const float* A    = (const float*)d_in[0];
    const float* Bd   = (const float*)d_in[1];
    const int*   rowi = (const int*)d_in[2];
    const int*   di   = (const int*)d_in[3];
    float*       C    = (float*)d_out;

    dim3 grid(16 * 64);   // 16 m-chunks x 64 columns, m-chunk-major
    dim3 block(512);
    hipLaunchKernelGGL(sparse_linear_kernel, grid, block, 0, stream,
                       A, Bd, rowi, di, C);
}

// Round 6
// 72.490 us; speedup vs baseline: 4.3867x; 4.3867x over previous
//
#include <hip/hip_runtime.h>
#include <hip/hip_bf16.h>

typedef __bf16 bf16x8 __attribute__((ext_vector_type(8)));
typedef float  f32x4  __attribute__((ext_vector_type(4)));

// 512 threads = 8 waves per block; one output column-block c, 512 M-rows
// (64 per wave). B (4 nonzero 64x64 blocks of column c) staged ONCE to LDS
// (bf16, [s][n][k] transposed, XOR-swizzled) by all 8 waves; A fragments
// loaded directly from global (fp32), converted in-register. Main loop:
// 16 steps (mt x s), depth-2 prefetch, barrier-free.
// __launch_bounds__(512,4): VGPR cap 128 (kernel needs ~60 — round 5's (512,8)
// cap of 64-effective forced spills: WRITE_SIZE 150->498 MB, 4x slowdown).
// Residency target: VGPR<=64 -> 8 waves/SIMD; LDS 4 blocks x 32KB = 128KB;
// grid 1024 = exactly 4 blocks/CU co-resident, zero tail.
__global__ __launch_bounds__(512, 4) void sparse_linear_kernel(
    const float* __restrict__ A, const float* __restrict__ Bd,
    const int* __restrict__ rowi, const int* __restrict__ di,
    float* __restrict__ C)
{
    __shared__ __align__(16) unsigned short Bt[4 * 64 * 64];   // 32 KB
    char* BtB = (char*)Bt;

    const int bid = blockIdx.x;
    const int c   = bid & 63;          // m-chunk-major: A-panel sharers concurrent -> L3 reuse
    const int mch = bid >> 6;          // 0..15
    const int t    = threadIdx.x;
    const int lane = t & 63;
    const int w    = t >> 6;           // 0..7

    int rs[4], ds[4];
    #pragma unroll
    for (int s = 0; s < 4; ++s) {
        rs[s] = rowi[s * 64 + c];
        ds[s] = di[s * 64 + c];
    }
    int koff[4];
    #pragma unroll
    for (int s = 0; s < 4; ++s) koff[s] = rs[s] * 64;

    const long mbase = (long)mch * 512 + w * 64;
    const float* Abase = A + (mbase + (lane & 15)) * 4096 + (lane >> 4) * 8;

    // ---- prologue: prefetch steps 0 and 1 (mt=0; s=0,1) ----
    float4 pf[2][4];
    #pragma unroll
    for (int st = 0; st < 2; ++st) {
        const float* p = Abase + koff[st];
        pf[st][0] = *(const float4*)(p);
        pf[st][1] = *(const float4*)(p + 4);
        pf[st][2] = *(const float4*)(p + 32);
        pf[st][3] = *(const float4*)(p + 36);
    }

    // ---- stage B once: 512 threads; thread owns (col n, k-half kh) of block sb ----
    {
        const int n  = t & 63;
        const int kh = (t >> 6) & 1;       // k rows [kh*32, kh*32+32)
        const int sb = t >> 7;             // 0..3
        const float* Bg = Bd + (long)ds[sb] * 64 + (long)kh * 32 * 16384 + n;
        char* dst = BtB + sb * 8192 + n * 128;
        const int sw = (n & 7) << 4;
        #pragma unroll
        for (int k4 = 0; k4 < 8; ++k4) {
            union { ushort4 u; __bf16 e[4]; } pk;
            pk.e[0] = (__bf16)Bg[(long)(4 * k4 + 0) * 16384];
            pk.e[1] = (__bf16)Bg[(long)(4 * k4 + 1) * 16384];
            pk.e[2] = (__bf16)Bg[(long)(4 * k4 + 2) * 16384];
            pk.e[3] = (__bf16)Bg[(long)(4 * k4 + 3) * 16384];
            *(ushort4*)(dst + ((kh * 64 + 8 * k4) ^ sw)) = pk.u;
        }
    }
    __syncthreads();   // the only barrier

    f32x4 acc[4];
    #pragma unroll
    for (int n2 = 0; n2 < 4; ++n2) acc[n2] = f32x4{0.f, 0.f, 0.f, 0.f};

    #pragma unroll
    for (int step = 0; step < 16; ++step) {
        const int mt = step >> 2, s = step & 3, slot = step & 1;

        // convert this step's A fragments (consumes pf[slot])
        union { bf16x8 v; __bf16 e[8]; } af0, af1;
        {
            const float4 a0 = pf[slot][0], a1 = pf[slot][1];
            const float4 a2 = pf[slot][2], a3 = pf[slot][3];
            af0.e[0] = (__bf16)a0.x; af0.e[1] = (__bf16)a0.y;
            af0.e[2] = (__bf16)a0.z; af0.e[3] = (__bf16)a0.w;
            af0.e[4] = (__bf16)a1.x; af0.e[5] = (__bf16)a1.y;
            af0.e[6] = (__bf16)a1.z; af0.e[7] = (__bf16)a1.w;
            af1.e[0] = (__bf16)a2.x; af1.e[1] = (__bf16)a2.y;
            af1.e[2] = (__bf16)a2.z; af1.e[3] = (__bf16)a2.w;
            af1.e[4] = (__bf16)a3.x; af1.e[5] = (__bf16)a3.y;
            af1.e[6] = (__bf16)a3.z; af1.e[7] = (__bf16)a3.w;
        }

        // re-issue freed slot for step+2 (WAR orders this after the converts)
        if (step + 2 < 16) {
            const int mt2 = (step + 2) >> 2, s2 = (step + 2) & 3;
            const float* p = Abase + (long)mt2 * (16 * 4096) + koff[s2];
            pf[slot][0] = *(const float4*)(p);
            pf[slot][1] = *(const float4*)(p + 4);
            pf[slot][2] = *(const float4*)(p + 32);
            pf[slot][3] = *(const float4*)(p + 36);
        }

        // 8 MFMAs for this (mt, s)
        const char* bbase = BtB + s * 8192;
        __builtin_amdgcn_s_setprio(1);
        #pragma unroll
        for (int kh = 0; kh < 2; ++kh) {
            const bf16x8 afv = kh ? af1.v : af0.v;
            const int kb = kh * 64 + (lane >> 4) * 16;
            #pragma unroll
            for (int n2 = 0; n2 < 4; ++n2) {
                const int nr = n2 * 16 + (lane & 15);
                bf16x8 bf = *(const bf16x8*)(bbase + nr * 128 + (kb ^ ((nr & 7) << 4)));
                acc[n2] = __builtin_amdgcn_mfma_f32_16x16x32_bf16(afv, bf, acc[n2], 0, 0, 0);
            }
        }
        __builtin_amdgcn_s_setprio(0);

        // C write at end of each m-tile (NT: keep A/B resident in caches)
        if (s == 3) {
            const long crow0 = mbase + mt * 16 + (lane >> 4) * 4;
            const long col0  = (long)c * 64 + (lane & 15);
            #pragma unroll
            for (int n2 = 0; n2 < 4; ++n2) {
                #pragma unroll
                for (int v = 0; v < 4; ++v)
                    __builtin_nontemporal_store(acc[n2][v],
                        &C[(crow0 + v) * 4096 + col0 + n2 * 16]);
                acc[n2] = f32x4{0.f, 0.f, 0.f, 0.f};
            }
        }
    }
}

extern "C" void kernel_launch(void* const* d_in, const int* in_sizes, int n_in,
                              void* d_out, int out_size, void* d_ws, size_t ws_size,
                              hipStream_t stream) {
    const float* A    = (const float*)d_in[0];
    const float* Bd   = (const float*)d_in[1];
    const int*   rowi = (const int*)d_in[2];
    const int*   di   = (const int*)d_in[3];
    float*       C    = (float*)d_out;

    dim3 grid(16 * 64);   // 16 m-chunks x 64 columns, m-chunk-major; 1024 blocks = 4/CU
    dim3 block(512);
    hipLaunchKernelGGL(sparse_linear_kernel, grid, block, 0, stream,
                       A, Bd, rowi, di, C);
}